// Round 1
// baseline (590.293 us; speedup 1.0000x reference)
//
#include <hip/hip_runtime.h>
#include <math.h>

// SpectralConv (FNO): B=4, CIN=COUT=32, D=64^3, modes 32x32x17
static constexpr int NB  = 4;
static constexpr int NC  = 32;
static constexpr int ND  = 64;
static constexpr int NM  = 32;
static constexpr int NK3 = 17;

__device__ __forceinline__ void build_tw(float2* tw, int t) {
    if (t < 64) {
        float s, c;
        sincosf((6.283185307179586f / 64.0f) * (float)t, &s, &c);
        tw[t] = make_float2(c, s);   // (cos, sin) of 2*pi*t/64
    }
}

// K1: rfft along d3, keep 17 bins. grid = B*C*64 (block per (b,c,d1)), block=64, lane=d2
__global__ __launch_bounds__(64)
void k1_rfft_d3(const float* __restrict__ x, float2* __restrict__ o1) {
    __shared__ float tile[64 * 65];
    __shared__ float2 tw[64];
    const int t = threadIdx.x;
    build_tw(tw, t);
    const int bid = blockIdx.x;                // (b*32+c)*64 + d1
    const float4* src4 = (const float4*)(x + (size_t)bid * 4096);
    for (int j = 0; j < 16; ++j) {             // stage 64x64 floats, padded rows
        int f4 = j * 64 + t;
        float4 v = src4[f4];
        int d2 = f4 >> 4;
        int n0 = (f4 & 15) << 2;
        float* p = &tile[d2 * 65 + n0];
        p[0] = v.x; p[1] = v.y; p[2] = v.z; p[3] = v.w;
    }
    __syncthreads();
    float ar[NK3], ai[NK3];
#pragma unroll
    for (int k = 0; k < NK3; ++k) { ar[k] = 0.f; ai[k] = 0.f; }
    const float* row = &tile[t * 65];
    for (int n = 0; n < 64; ++n) {
        float xv = row[n];
#pragma unroll
        for (int k = 0; k < NK3; ++k) {        // e^{-i*2pi*k*n/64}
            float2 w = tw[(n * k) & 63];
            ar[k] += xv * w.x;
            ai[k] -= xv * w.y;
        }
    }
    const int bc = bid >> 6, d1 = bid & 63;
    float2* dst = o1 + (size_t)bc * (NK3 * 4096) + d1 * 64 + t;   // (b,c,k3,d1,d2)
#pragma unroll
    for (int k = 0; k < NK3; ++k)
        dst[(size_t)k * 4096] = make_float2(ar[k], ai[k]);
}

// K2: forward 2D DFT over (d1,d2), keep 32 centered freqs per axis (o=(p+48)&63).
// grid = B*C*17 (block per plane), block=256
__global__ __launch_bounds__(256)
void k2_fft2d(const float2* __restrict__ in, float2* __restrict__ o) {
    __shared__ float2 P[64 * 65];
    __shared__ float2 T[64 * 33];
    __shared__ float2 tw[64];
    const int t = threadIdx.x;
    build_tw(tw, t);
    const size_t base = (size_t)blockIdx.x * 4096;
    for (int j = 0; j < 16; ++j) {
        int idx = j * 256 + t;
        P[(idx >> 6) * 65 + (idx & 63)] = in[base + idx];
    }
    __syncthreads();
    const int p2 = t & 31, g = t >> 5;
    const int o2 = (p2 + 48) & 63;
    for (int j = 0; j < 8; ++j) {              // DFT along d2
        int d1 = g + (j << 3);
        const float2* prow = &P[d1 * 65];
        float sr = 0.f, si = 0.f;
        int idx = 0;                           // (o2*n2) mod 64, incremental
        for (int n2 = 0; n2 < 64; ++n2) {
            float2 xv = prow[n2];
            float2 w = tw[idx];
            sr += xv.x * w.x + xv.y * w.y;     // x * e^{-i th}
            si += xv.y * w.x - xv.x * w.y;
            idx = (idx + o2) & 63;
        }
        T[d1 * 33 + p2] = make_float2(sr, si);
    }
    __syncthreads();
    float2* dst = o + (size_t)blockIdx.x * 1024;   // (b,c,k3,p1,p2)
    for (int j = 0; j < 4; ++j) {              // DFT along d1
        int p1 = g + (j << 3);
        int o1 = (p1 + 48) & 63;
        float sr = 0.f, si = 0.f;
        int idx = 0;
        for (int n1 = 0; n1 < 64; ++n1) {
            float2 xv = T[n1 * 33 + p2];
            float2 w = tw[idx];
            sr += xv.x * w.x + xv.y * w.y;
            si += xv.y * w.x - xv.x * w.y;
            idx = (idx + o1) & 63;
        }
        dst[p1 * 32 + p2] = make_float2(sr, si);
    }
}

// K3: per-mode complex channel mix out[b,f,m] = sum_c xs[b,c,m]*w[c,f,m]
// grid = (17408/64, 8 cout-chunks), block=64; lane = consecutive weight-layout mode
__global__ __launch_bounds__(64)
void k3_mix(const float2* __restrict__ xs, const float* __restrict__ wr,
            const float* __restrict__ wi, float2* __restrict__ o) {
    const int t = threadIdx.x;
    const int m = blockIdx.x * 64 + t;         // (p1*32+p2)*17 + k3  (weight layout)
    const int chunk = blockIdx.y;              // 4 couts per chunk
    const int k3 = m % 17;
    const int pp = m / 17;
    const int mo = k3 * 1024 + pp;             // (k3,p1,p2) buffer layout
    float ar[4][4], ai[4][4];
#pragma unroll
    for (int a = 0; a < 4; ++a)
#pragma unroll
        for (int co = 0; co < 4; ++co) { ar[a][co] = 0.f; ai[a][co] = 0.f; }
    for (int cin = 0; cin < 32; ++cin) {
        float2 xv[4];
#pragma unroll
        for (int a = 0; a < 4; ++a)
            xv[a] = xs[((size_t)a * 32 + cin) * 17408 + mo];
        size_t wb = ((size_t)cin * 32 + chunk * 4) * 17408 + m;
#pragma unroll
        for (int co = 0; co < 4; ++co) {
            float wrv = wr[wb + (size_t)co * 17408];
            float wiv = wi[wb + (size_t)co * 17408];
#pragma unroll
            for (int a = 0; a < 4; ++a) {
                ar[a][co] += xv[a].x * wrv - xv[a].y * wiv;
                ai[a][co] += xv[a].x * wiv + xv[a].y * wrv;
            }
        }
    }
#pragma unroll
    for (int a = 0; a < 4; ++a)
#pragma unroll
        for (int co = 0; co < 4; ++co)
            o[((size_t)a * 32 + chunk * 4 + co) * 17408 + mo] =
                make_float2(ar[a][co], ai[a][co]);
}

// K4: inverse 2D DFT (32 modes -> 64 points per axis), e^{+i th}. grid = B*C*17, block=256
__global__ __launch_bounds__(256)
void k4_ifft2d(const float2* __restrict__ in, float2* __restrict__ o) {
    __shared__ float2 Xm[32 * 33];
    __shared__ float2 U[64 * 33];
    __shared__ float2 tw[64];
    const int t = threadIdx.x;
    build_tw(tw, t);
    const size_t base = (size_t)blockIdx.x * 1024;
    for (int j = 0; j < 4; ++j) {
        int idx = j * 256 + t;
        Xm[(idx >> 5) * 33 + (idx & 31)] = in[base + idx];
    }
    __syncthreads();
    const int p2 = t & 31, g = t >> 5;
    for (int j = 0; j < 8; ++j) {              // inverse along d1
        int n1 = g + (j << 3);
        float sr = 0.f, si = 0.f;
        int idx = (48 * n1) & 63;              // ((p1+48)*n1) mod 64, incremental
        for (int p1 = 0; p1 < 32; ++p1) {
            float2 xv = Xm[p1 * 33 + p2];
            float2 w = tw[idx];
            sr += xv.x * w.x - xv.y * w.y;     // x * e^{+i th}
            si += xv.y * w.x + xv.x * w.y;
            idx = (idx + n1) & 63;
        }
        U[n1 * 33 + p2] = make_float2(sr, si);
    }
    __syncthreads();
    const int n2 = t & 63, g2 = t >> 6;
    float2* dst = o + (size_t)blockIdx.x * 4096;   // (b,f,k3,n1,n2)
    for (int j = 0; j < 16; ++j) {             // inverse along d2
        int n1 = g2 + (j << 2);
        float sr = 0.f, si = 0.f;
        int idx = (48 * n2) & 63;
        for (int p2i = 0; p2i < 32; ++p2i) {
            float2 xv = U[n1 * 33 + p2i];
            float2 w = tw[idx];
            sr += xv.x * w.x - xv.y * w.y;
            si += xv.y * w.x + xv.x * w.y;
            idx = (idx + n2) & 63;
        }
        dst[n1 * 64 + n2] = make_float2(sr, si);
    }
}

// K5: inverse rfft along d3 (17 bins of 33 nonzero) + 1/64^3 + bias.
// grid = B*C*64 (block per (b,f,d1)), block=64, lane=d2
__global__ __launch_bounds__(64)
void k5_irfft_d3(const float2* __restrict__ in, const float* __restrict__ bias,
                 float* __restrict__ out) {
    __shared__ float ytile[64 * 65];
    __shared__ float2 tw[64];
    const int t = threadIdx.x;
    build_tw(tw, t);
    const int bid = blockIdx.x;                // (b*32+f)*64 + d1
    const int bf = bid >> 6, d1 = bid & 63;
    const float2* src = in + (size_t)bf * (NK3 * 4096) + d1 * 64 + t;
    float xr[NK3], xi[NK3];
    {
        const float inv = 1.0f / 262144.0f;    // 1/64^3
        float2 v0 = src[0];
        xr[0] = v0.x * inv;                    // imag of bin 0 dropped (numpy irfft)
        xi[0] = 0.f;
#pragma unroll
        for (int k = 1; k < NK3; ++k) {
            float2 v = src[(size_t)k * 4096];
            xr[k] = v.x * (2.f * inv);
            xi[k] = v.y * (2.f * inv);
        }
    }
    __syncthreads();                           // tw ready
    const float bv = bias[bf & 31];
    for (int n = 0; n < 64; ++n) {
        float y = xr[0];
#pragma unroll
        for (int k = 1; k < NK3; ++k) {        // + 2*Re(X[k] e^{+i 2pi k n/64})
            float2 w = tw[(k * n) & 63];
            y += xr[k] * w.x - xi[k] * w.y;
        }
        ytile[t * 65 + n] = y + bv;
    }
    __syncthreads();
    float* dst = out + (size_t)bid * 4096;     // (b,f,d1,d2,n3), contiguous n3
    for (int d2 = 0; d2 < 64; ++d2)
        dst[d2 * 64 + t] = ytile[d2 * 65 + t];
}

extern "C" void kernel_launch(void* const* d_in, const int* in_sizes, int n_in,
                              void* d_out, int out_size, void* d_ws, size_t ws_size,
                              hipStream_t stream) {
    const float* x    = (const float*)d_in[0];
    const float* wr   = (const float*)d_in[1];
    const float* wi   = (const float*)d_in[2];
    const float* bias = (const float*)d_in[3];
    float* out = (float*)d_out;

    // workspace: buf1 (b,c,k3,64,64) f2 = 71.3MB; buf2/buf3 (b,c|f,k3,32,32) f2 = 17.8MB each
    float2* buf1 = (float2*)d_ws;
    float2* buf2 = buf1 + (size_t)NB * NC * NK3 * 4096;
    float2* buf3 = buf2 + (size_t)NB * NC * NK3 * 1024;

    k1_rfft_d3 <<<NB * NC * ND,  64, 0, stream>>>(x, buf1);
    k2_fft2d   <<<NB * NC * NK3, 256, 0, stream>>>(buf1, buf2);
    dim3 g3(NM * NM * NK3 / 64, 8);
    k3_mix     <<<g3, 64, 0, stream>>>(buf2, wr, wi, buf3);
    k4_ifft2d  <<<NB * NC * NK3, 256, 0, stream>>>(buf3, buf1);   // buf1 reused
    k5_irfft_d3<<<NB * NC * ND,  64, 0, stream>>>(buf1, bias, out);
}

// Round 2
// 362.720 us; speedup vs baseline: 1.6274x; 1.6274x over previous
//
#include <hip/hip_runtime.h>
#include <math.h>

// SpectralConv (FNO): B=4, CIN=COUT=32, D=64^3, modes 32x32x17
// Pipeline: k1 (rfft d3) -> k2a (dft d2) -> k2b (dft d1, ->weight layout)
//           -> k3 (channel mix) -> k4a (idft d1) -> k4b (idft d2) -> k5 (irfft d3 + bias)
static constexpr int NB  = 4;
static constexpr int NC  = 32;

// Twiddle tables (filled by k0_init each launch; module globals, not ws).
// T3F[n][k]  = e^{-2pi i nk/64}, rows padded to 48 floats (17 cpx used)
// T3I[n][k]  = e^{+2pi i nk/64}
// T12F[n][p] = e^{-2pi i o(p) n/64}, o(p) = (p+48)&63, rows 64 floats (32 cpx)
// TINV[p][n] = e^{+2pi i o(p) n/64}, rows 128 floats (64 cpx)
__device__ __attribute__((aligned(256))) float T3F[64 * 48];
__device__ __attribute__((aligned(256))) float T3I[64 * 48];
__device__ __attribute__((aligned(256))) float T12F[64 * 64];
__device__ __attribute__((aligned(256))) float TINV[32 * 128];

__global__ __launch_bounds__(256) void k0_init() {
    const int t = blockIdx.x * 256 + threadIdx.x;
    if (t < 64 * 17) {
        int n = t / 17, k = t % 17;
        int idx = (n * k) & 63;
        float s, c;
        sincospif(idx / 32.0f, &s, &c);      // theta = 2*pi*idx/64
        T3F[n * 48 + 2 * k] = c;  T3F[n * 48 + 2 * k + 1] = -s;
        T3I[n * 48 + 2 * k] = c;  T3I[n * 48 + 2 * k + 1] =  s;
    }
    if (t < 64) {
        for (int q = 34; q < 48; ++q) { T3F[t * 48 + q] = 0.f; T3I[t * 48 + q] = 0.f; }
    }
    if (t < 64 * 32) {
        int n = t / 32, p = t % 32;
        int o = (p + 48) & 63;
        int idx = (o * n) & 63;
        float s, c;
        sincospif(idx / 32.0f, &s, &c);
        T12F[n * 64 + 2 * p] = c;  T12F[n * 64 + 2 * p + 1] = -s;
    }
    if (t < 32 * 64) {
        int p = t / 64, n = t % 64;
        int o = (p + 48) & 63;
        int idx = (o * n) & 63;
        float s, c;
        sincospif(idx / 32.0f, &s, &c);
        TINV[p * 128 + 2 * n] = c;  TINV[p * 128 + 2 * n + 1] = s;
    }
}

__device__ __forceinline__ void cmadd(float2& a, float2 x, float wx, float wy) {
    a.x = fmaf(x.x, wx, fmaf(-x.y, wy, a.x));
    a.y = fmaf(x.x, wy, fmaf( x.y, wx, a.y));
}

// K1: rfft along d3, keep 17 bins. grid = B*C*64 (block per (b,c,d1)), block=64, lane=d2
// out layout: (b,c,k3,d1,d2)
__global__ __launch_bounds__(64)
void k1_rfft_d3(const float* __restrict__ x, float2* __restrict__ o1) {
    __shared__ float tile[64 * 65];
    const int t = threadIdx.x, bid = blockIdx.x;
    const float4* src4 = (const float4*)(x + (size_t)bid * 4096);
    for (int j = 0; j < 16; ++j) {
        int f4 = j * 64 + t;
        float4 v = src4[f4];
        int d2 = f4 >> 4, n0 = (f4 & 15) << 2;
        float* p = &tile[d2 * 65 + n0];
        p[0] = v.x; p[1] = v.y; p[2] = v.z; p[3] = v.w;
    }
    __syncthreads();
    float ar[17], ai[17];
#pragma unroll
    for (int k = 0; k < 17; ++k) { ar[k] = 0.f; ai[k] = 0.f; }
    const float* row = &tile[t * 65];
    for (int n = 0; n < 64; ++n) {
        float xv = row[n];
        const float* w = &T3F[n * 48];       // uniform -> s_load
#pragma unroll
        for (int k = 0; k < 17; ++k) {
            ar[k] = fmaf(xv, w[2 * k], ar[k]);
            ai[k] = fmaf(xv, w[2 * k + 1], ai[k]);
        }
    }
    const int bc = bid >> 6, d1 = bid & 63;
    float2* dst = o1 + (size_t)bc * (17 * 4096) + d1 * 64 + t;
#pragma unroll
    for (int k = 0; k < 17; ++k)
        dst[(size_t)k * 4096] = make_float2(ar[k], ai[k]);
}

// K2a: DFT along d2 -> 32 centered freqs. block per (b,c,k3) plane, 256 thr.
// in: (plane, d1, d2); out T: (plane, d1, p2)
__global__ __launch_bounds__(256)
void k2a_dft_d2(const float2* __restrict__ in, float2* __restrict__ T) {
    __shared__ float smem[8320];             // re[64*65] | im[64*65]; reused as float2 tile
    float* re = smem;
    float* im = smem + 64 * 65;
    const int t = threadIdx.x;
    const size_t base = (size_t)blockIdx.x * 4096;
    for (int j = 0; j < 16; ++j) {
        int idx = j * 256 + t;
        float2 v = in[base + idx];
        int d1 = idx >> 6, n2 = idx & 63;
        re[d1 * 65 + n2] = v.x;
        im[d1 * 65 + n2] = v.y;
    }
    __syncthreads();
    const int d1 = t & 63;
    const int pg = __builtin_amdgcn_readfirstlane(t >> 6);   // wave-uniform
    float2 acc[8];
#pragma unroll
    for (int j = 0; j < 8; ++j) acc[j] = make_float2(0.f, 0.f);
    const float* rrow = &re[d1 * 65];
    const float* irow = &im[d1 * 65];
#pragma unroll 2
    for (int n2 = 0; n2 < 64; ++n2) {
        float xr = rrow[n2], xi = irow[n2];
        const float* w = &T12F[n2 * 64 + pg * 16];           // uniform -> s_load
#pragma unroll
        for (int j = 0; j < 8; ++j)
            cmadd(acc[j], make_float2(xr, xi), w[2 * j], w[2 * j + 1]);
    }
    __syncthreads();
    float2* tile = (float2*)smem;            // [64][33]
#pragma unroll
    for (int j = 0; j < 8; ++j) tile[d1 * 33 + pg * 8 + j] = acc[j];
    __syncthreads();
    float2* dst = T + (size_t)blockIdx.x * 2048;
#pragma unroll
    for (int q = 0; q < 8; ++q) {
        int e = t * 8 + q;
        dst[e] = tile[(e >> 5) * 33 + (e & 31)];             // (d1,p2) linear
    }
}

// K2b: DFT along d1 -> weight-layout modes. grid (bc=128, p1g=4), block 544 (=17*32).
// in T: (bc,k3,n1,p2); out Y: (b,c, p1*544 + p2*17 + k3)
__global__ __launch_bounds__(544)
void k2b_dft_d1(const float2* __restrict__ T, float2* __restrict__ Y) {
    const int u = threadIdx.x;
    const int bc = blockIdx.x, pg = blockIdx.y;
    const int k3 = u % 17, p2 = u / 17;
    const float2* src = T + ((size_t)bc * 17 + k3) * 2048 + p2;
    float2 acc[8];
#pragma unroll
    for (int j = 0; j < 8; ++j) acc[j] = make_float2(0.f, 0.f);
#pragma unroll 2
    for (int n1 = 0; n1 < 64; ++n1) {
        float2 xv = src[n1 * 32];
        const float* w = &T12F[n1 * 64 + pg * 16];           // block-uniform -> s_load
#pragma unroll
        for (int j = 0; j < 8; ++j)
            cmadd(acc[j], xv, w[2 * j], w[2 * j + 1]);
    }
    float2* dst = Y + (size_t)bc * 17408 + (size_t)pg * 8 * 544 + u;
#pragma unroll
    for (int j = 0; j < 8; ++j) dst[(size_t)j * 544] = acc[j];
}

// K3: channel mix, weight layout. grid (272, 4 cout-chunks of 8), block 64.
__global__ __launch_bounds__(64)
void k3_mix(const float2* __restrict__ Y, const float* __restrict__ wr,
            const float* __restrict__ wi, float2* __restrict__ Z) {
    const int m = blockIdx.x * 64 + threadIdx.x;   // weight-layout mode
    const int ch = blockIdx.y;
    float2 acc[4][8];
#pragma unroll
    for (int a = 0; a < 4; ++a)
#pragma unroll
        for (int co = 0; co < 8; ++co) acc[a][co] = make_float2(0.f, 0.f);
    for (int cin = 0; cin < 32; ++cin) {
        float2 xv[4];
#pragma unroll
        for (int a = 0; a < 4; ++a)
            xv[a] = Y[((size_t)a * 32 + cin) * 17408 + m];
        size_t wb = ((size_t)cin * 32 + ch * 8) * 17408 + m;
#pragma unroll
        for (int co = 0; co < 8; ++co) {
            float wrv = wr[wb + (size_t)co * 17408];
            float wiv = wi[wb + (size_t)co * 17408];
#pragma unroll
            for (int a = 0; a < 4; ++a)
                cmadd(acc[a][co], xv[a], wrv, wiv);
        }
    }
#pragma unroll
    for (int a = 0; a < 4; ++a)
#pragma unroll
        for (int co = 0; co < 8; ++co)
            Z[((size_t)a * 32 + ch * 8 + co) * 17408 + m] = acc[a][co];
}

// K4a: inverse DFT along d1 (32 modes -> 64 pts). grid (bf=128, n1g=8), block 544.
// in Z: weight layout; out U: (bf, n1, p2*17+k3)
__global__ __launch_bounds__(544)
void k4a_idft_d1(const float2* __restrict__ Z, float2* __restrict__ U) {
    const int u = threadIdx.x;
    const int bf = blockIdx.x, ng = blockIdx.y;
    const float2* src = Z + (size_t)bf * 17408 + u;
    float2 acc[8];
#pragma unroll
    for (int j = 0; j < 8; ++j) acc[j] = make_float2(0.f, 0.f);
#pragma unroll 2
    for (int p1 = 0; p1 < 32; ++p1) {
        float2 xv = src[(size_t)p1 * 544];
        const float* w = &TINV[p1 * 128 + ng * 16];          // block-uniform -> s_load
#pragma unroll
        for (int j = 0; j < 8; ++j)
            cmadd(acc[j], xv, w[2 * j], w[2 * j + 1]);
    }
    float2* dst = U + (size_t)bf * 34816 + (size_t)ng * 8 * 544 + u;
#pragma unroll
    for (int j = 0; j < 8; ++j) dst[(size_t)j * 544] = acc[j];
}

// K4b: inverse DFT along d2 (32 -> 64). grid (bf=128, k3=17), block 256.
// in U: (bf, n1, p2*17+k3); out V: (bf, k3, n1, n2)
__global__ __launch_bounds__(256)
void k4b_idft_d2(const float2* __restrict__ U, float2* __restrict__ V) {
    __shared__ float smem[8320];             // re[64*33] | im[64*33]; reused as float2 tile [64][65]
    float* re = smem;
    float* im = smem + 64 * 33;
    const int t = threadIdx.x;
    const int bf = blockIdx.x, k3 = blockIdx.y;
    const float2* src = U + (size_t)bf * 34816 + k3;
#pragma unroll
    for (int q = 0; q < 8; ++q) {
        int e = t * 8 + q;
        float2 v = src[(size_t)(e >> 5) * 544 + (e & 31) * 17];
        re[(e >> 5) * 33 + (e & 31)] = v.x;
        im[(e >> 5) * 33 + (e & 31)] = v.y;
    }
    __syncthreads();
    const int n1 = t & 63;
    const int ng = __builtin_amdgcn_readfirstlane(t >> 6);
    float2 acc[16];
#pragma unroll
    for (int j = 0; j < 16; ++j) acc[j] = make_float2(0.f, 0.f);
    for (int p2 = 0; p2 < 32; ++p2) {
        float xr = re[n1 * 33 + p2], xi = im[n1 * 33 + p2];
        const float* w = &TINV[p2 * 128 + ng * 32];          // wave-uniform -> s_load
#pragma unroll
        for (int j = 0; j < 16; ++j)
            cmadd(acc[j], make_float2(xr, xi), w[2 * j], w[2 * j + 1]);
    }
    __syncthreads();
    float2* tile = (float2*)smem;            // [64][65]
#pragma unroll
    for (int j = 0; j < 16; ++j) tile[n1 * 65 + ng * 16 + j] = acc[j];
    __syncthreads();
    float2* dst = V + ((size_t)bf * 17 + k3) * 4096;
#pragma unroll
    for (int q = 0; q < 16; ++q) {
        int e = t * 16 + q;
        dst[e] = tile[(e >> 6) * 65 + (e & 63)];
    }
}

// K5: irfft along d3 (17 bins) + scale + bias. grid = B*C*64, block 64, lane=d2.
__global__ __launch_bounds__(64)
void k5_irfft_d3(const float2* __restrict__ V, const float* __restrict__ bias,
                 float* __restrict__ out) {
    __shared__ float ytile[64 * 65];
    const int t = threadIdx.x, bid = blockIdx.x;
    const int bf = bid >> 6, d1 = bid & 63;
    const float2* src = V + (size_t)bf * (17 * 4096) + d1 * 64 + t;
    float xr[17], xi[17];
    const float inv = 1.0f / 262144.0f;      // 1/64^3
    {
        float2 v0 = src[0];
        xr[0] = v0.x * inv;                  // imag of bin 0 dropped (numpy irfft)
        xi[0] = 0.f;
#pragma unroll
        for (int k = 1; k < 17; ++k) {
            float2 v = src[(size_t)k * 4096];
            xr[k] = v.x * (2.f * inv);
            xi[k] = v.y * (2.f * inv);
        }
    }
    const float bv = bias[bf & 31];
    for (int n = 0; n < 64; ++n) {
        const float* w = &T3I[n * 48];       // uniform -> s_load
        float y = bv;
#pragma unroll
        for (int k = 0; k < 17; ++k)
            y = fmaf(xr[k], w[2 * k], fmaf(-xi[k], w[2 * k + 1], y));
        ytile[t * 65 + n] = y;
    }
    __syncthreads();
    float* dst = out + (size_t)bid * 4096;
    for (int d2 = 0; d2 < 64; ++d2)
        dst[d2 * 64 + t] = ytile[d2 * 65 + t];
}

extern "C" void kernel_launch(void* const* d_in, const int* in_sizes, int n_in,
                              void* d_out, int out_size, void* d_ws, size_t ws_size,
                              hipStream_t stream) {
    const float* x    = (const float*)d_in[0];
    const float* wr   = (const float*)d_in[1];
    const float* wi   = (const float*)d_in[2];
    const float* bias = (const float*)d_in[3];
    float* out = (float*)d_out;

    // ws regions (total 106,954,752 B, same as previously-passing usage):
    //   A: 71,303,168 B (2176 planes * 4096 cpx)
    //   B: 35,651,584 B (2176 planes * 2048 cpx)
    // Liveness: K1->A; K2a A->B; K2b B->A[0:17.8M]; K3 A[0:17.8M]->A[17.8:35.7M];
    //           K4a A[17.8:35.7M]->B; K4b B->A(full); K5 A->out.
    float2* A = (float2*)d_ws;
    float2* B = A + (size_t)2176 * 4096;
    float2* Y = A;                                   // 17,825,792 B
    float2* Z = A + (size_t)17825792 / 8;            // next 17,825,792 B

    k0_init    <<<8, 256, 0, stream>>>();
    k1_rfft_d3 <<<NB * NC * 64, 64, 0, stream>>>(x, A);
    k2a_dft_d2 <<<2176, 256, 0, stream>>>(A, B);
    k2b_dft_d1 <<<dim3(128, 4), 544, 0, stream>>>(B, Y);
    k3_mix     <<<dim3(272, 4), 64, 0, stream>>>(Y, wr, wi, Z);
    k4a_idft_d1<<<dim3(128, 8), 544, 0, stream>>>(Z, B);
    k4b_idft_d2<<<dim3(128, 17), 256, 0, stream>>>(B, A);
    k5_irfft_d3<<<NB * NC * 64, 64, 0, stream>>>(A, bias, out);
}